// Round 1
// baseline (63.481 us; speedup 1.0000x reference)
//
#include <hip/hip_runtime.h>

// Problem constants (match reference file)
#define ND   512          // D
#define NN   8192         // N
#define NP1  8193         // N+1
#define NROWS 1025        // 2D+1
#define LMBDF 0.9f

// ---------------------------------------------------------------------------
// Kernel 1: v[j] = sum_{i>=j} z[i] * lmbd^(i-j), z = last row of Z.
// Truncate at 768 terms (0.9^768 ~ 1e-35, below fp32 resolution).
// 4 independent accumulator chains for ILP.
// ---------------------------------------------------------------------------
__global__ void k_v(const float* __restrict__ Z, float* __restrict__ v) {
    int j = blockIdx.x * blockDim.x + threadIdx.x;
    if (j > NN) return;
    if (j == NN) { v[j] = 0.0f; return; }
    const float* z = Z + (size_t)(2 * ND) * NP1;
    int kmax = NN - j;
    if (kmax > 768) kmax = 768;
    const float l1 = LMBDF;
    const float l2 = l1 * l1;
    const float l3 = l2 * l1;
    const float l4 = l2 * l2;
    float p0 = 1.0f, p1 = l1, p2 = l2, p3 = l3;
    float a0 = 0.f, a1 = 0.f, a2 = 0.f, a3 = 0.f;
    int k = 0;
    for (; k + 3 < kmax; k += 4) {
        a0 = fmaf(p0, z[j + k + 0], a0);
        a1 = fmaf(p1, z[j + k + 1], a1);
        a2 = fmaf(p2, z[j + k + 2], a2);
        a3 = fmaf(p3, z[j + k + 3], a3);
        p0 *= l4; p1 *= l4; p2 *= l4; p3 *= l4;
    }
    for (; k < kmax; ++k) { a0 = fmaf(p0, z[j + k], a0); p0 *= l1; }
    v[j] = (a0 + a2) + (a1 + a3);
}

// ---------------------------------------------------------------------------
// Kernel 2: w[c] = sum_{j<N} Z[c,j] * v[j], one block per row c (c < D).
// ---------------------------------------------------------------------------
__global__ void k_w(const float* __restrict__ Z, const float* __restrict__ v,
                    float* __restrict__ w) {
    int c = blockIdx.x;
    const float* row = Z + (size_t)c * NP1;
    float acc = 0.0f;
    for (int j = threadIdx.x; j < NN; j += blockDim.x)
        acc = fmaf(row[j], v[j], acc);
    // wave reduce (64 lanes)
    for (int off = 32; off > 0; off >>= 1)
        acc += __shfl_down(acc, off, 64);
    __shared__ float red[4];
    if ((threadIdx.x & 63) == 0) red[threadIdx.x >> 6] = acc;
    __syncthreads();
    if (threadIdx.x == 0) w[c] = (red[0] + red[1]) + (red[2] + red[3]);
}

// ---------------------------------------------------------------------------
// Kernel 3: out = Z (float4 grid-stride copy; 1 scalar tail element).
// ---------------------------------------------------------------------------
__global__ void k_copy(const float4* __restrict__ src, float4* __restrict__ dst,
                       const float* __restrict__ ssrc, float* __restrict__ sdst) {
    const size_t total4 = ((size_t)NROWS * NP1) / 4;   // 2,099,456
    size_t stride = (size_t)gridDim.x * blockDim.x;
    for (size_t i = (size_t)blockIdx.x * blockDim.x + threadIdx.x; i < total4; i += stride)
        dst[i] = src[i];
    if (blockIdx.x == 0 && threadIdx.x == 0) {
        const size_t last = (size_t)NROWS * NP1 - 1;
        sdst[last] = ssrc[last];
    }
}

// ---------------------------------------------------------------------------
// Kernel 4: partial u: for c-chunk cy (64 rows), per column j:
//   upart[cy][j] = sum_{c in chunk} w[c] * (Z[c+D,j] - Z[c,j])
// ---------------------------------------------------------------------------
__global__ void k_u(const float* __restrict__ Z, const float* __restrict__ w,
                    float* __restrict__ upart) {
    int j = blockIdx.x * blockDim.x + threadIdx.x;
    int cy = blockIdx.y;
    if (j >= NP1) return;
    float acc = 0.0f;
    int c0 = cy * 64;
#pragma unroll 4
    for (int c = c0; c < c0 + 64; ++c) {
        float wc = w[c];  // uniform -> scalar load
        float lo = Z[(size_t)c * NP1 + j];
        float hi = Z[(size_t)(c + ND) * NP1 + j];
        acc = fmaf(wc, hi - lo, acc);
    }
    upart[(size_t)cy * NP1 + j] = acc;
}

// ---------------------------------------------------------------------------
// Kernel 5: finalize last row: out[2D, j] = Z[2D, j] + (alpha/N) * u[j]
// ---------------------------------------------------------------------------
__global__ void k_fin(const float* __restrict__ Z, const float* __restrict__ upart,
                      const float* __restrict__ alpha, float* __restrict__ out) {
    int j = blockIdx.x * blockDim.x + threadIdx.x;
    if (j >= NP1) return;
    float u = 0.0f;
#pragma unroll
    for (int k = 0; k < 8; ++k) u += upart[(size_t)k * NP1 + j];
    float s = alpha[0] / (float)NN;
    const size_t off = (size_t)(2 * ND) * NP1 + j;
    out[off] = fmaf(s, u, Z[off]);
}

extern "C" void kernel_launch(void* const* d_in, const int* in_sizes, int n_in,
                              void* d_out, int out_size, void* d_ws, size_t ws_size,
                              hipStream_t stream) {
    const float* Z     = (const float*)d_in[0];
    const float* alpha = (const float*)d_in[1];
    // d_in[2..4] = P, M, Q: structure is hardcoded (P one-hot, M = lmbd^(i-j)
    // lower-tri, Q = [[-I, I], [0, 0]]).
    float* out = (float*)d_out;

    // workspace layout (floats): v[NP1] | w[ND] | upart[8*NP1]
    float* v     = (float*)d_ws;
    float* w     = v + NP1;
    float* upart = w + ND;

    // 1) decayed suffix scan of last row
    k_v<<<(NP1 + 255) / 256, 256, 0, stream>>>(Z, v);
    // 2) w = Z[0:D,:] @ v
    k_w<<<ND, 256, 0, stream>>>(Z, v, w);
    // 3) out = Z
    k_copy<<<2048, 256, 0, stream>>>((const float4*)Z, (float4*)out, Z, out);
    // 4) u partials over 8 chunks of 64 c's
    dim3 gu((NP1 + 255) / 256, 8);
    k_u<<<gu, 256, 0, stream>>>(Z, w, upart);
    // 5) last row update
    k_fin<<<(NP1 + 255) / 256, 256, 0, stream>>>(Z, upart, alpha, out);
}

// Round 2
// 31.983 us; speedup vs baseline: 1.9848x; 1.9848x over previous
//
#include <hip/hip_runtime.h>

// Problem constants (match reference file)
#define ND   512          // D
#define NN   8192         // N
#define NP1  8193         // N+1
#define NROWS 1025        // 2D+1
#define NCHUNK 16         // row-pair chunks for u partials

// ---------------------------------------------------------------------------
// Kernel 1: v[j] = sum_{k>=0} z[j+k] * lmbd^k, z = last row of Z.
// Truncated at 192 terms (0.9^192/(1-0.9) ~ 1.6e-8, way below threshold).
// 4 lanes cooperate per column j (48 terms each), shfl_xor combine.
// ---------------------------------------------------------------------------
__global__ void k_v(const float* __restrict__ Z, float* __restrict__ v) {
    int tid = threadIdx.x;
    int jj = blockIdx.x * 64 + (tid >> 2);
    if (jj > NN) return;
    int p = tid & 3;
    if (jj == NN) { if (p == 0) v[jj] = 0.0f; return; }
    const float* z = Z + (size_t)(2 * ND) * NP1;
    const float l1 = 0.9f;
    const float l2 = l1 * l1, l4 = l2 * l2, l8 = l4 * l4;
    const float l16 = l8 * l8, l32 = l16 * l16, l48 = l32 * l16;
    float scale = (p == 0) ? 1.0f
                : (p == 1) ? l48
                : (p == 2) ? l48 * l48
                           : l48 * l48 * l48;
    int base = jj + 48 * p;
    float p0 = scale, p1 = scale * l1, p2 = scale * l2, p3 = scale * l2 * l1;
    float a0 = 0.f, a1 = 0.f, a2 = 0.f, a3 = 0.f;
#pragma unroll
    for (int m = 0; m < 48; m += 4) {
        int i = base + m;
        float z0 = (i     < NN) ? z[i]     : 0.0f;
        float z1 = (i + 1 < NN) ? z[i + 1] : 0.0f;
        float z2 = (i + 2 < NN) ? z[i + 2] : 0.0f;
        float z3 = (i + 3 < NN) ? z[i + 3] : 0.0f;
        a0 = fmaf(p0, z0, a0);
        a1 = fmaf(p1, z1, a1);
        a2 = fmaf(p2, z2, a2);
        a3 = fmaf(p3, z3, a3);
        p0 *= l4; p1 *= l4; p2 *= l4; p3 *= l4;
    }
    float a = (a0 + a2) + (a1 + a3);
    a += __shfl_xor(a, 1, 64);
    a += __shfl_xor(a, 2, 64);
    if (p == 0) v[jj] = a;
}

// ---------------------------------------------------------------------------
// Kernel 2: w[c] = sum_{j<N} Z[c,j] * v[j], one block (256 thr) per row c < D.
// 4-way unrolled strided reduction, coalesced.
// ---------------------------------------------------------------------------
__global__ void k_w(const float* __restrict__ Z, const float* __restrict__ v,
                    float* __restrict__ w) {
    int c = blockIdx.x;
    const float* row = Z + (size_t)c * NP1;
    float a0 = 0.f, a1 = 0.f, a2 = 0.f, a3 = 0.f;
    // NN = 8192 = 8 * 1024 exactly; no guards needed
    for (int j = threadIdx.x; j < NN; j += 1024) {
        a0 = fmaf(row[j],       v[j],       a0);
        a1 = fmaf(row[j + 256], v[j + 256], a1);
        a2 = fmaf(row[j + 512], v[j + 512], a2);
        a3 = fmaf(row[j + 768], v[j + 768], a3);
    }
    float acc = (a0 + a2) + (a1 + a3);
    for (int off = 32; off > 0; off >>= 1)
        acc += __shfl_down(acc, off, 64);
    __shared__ float red[4];
    if ((threadIdx.x & 63) == 0) red[threadIdx.x >> 6] = acc;
    __syncthreads();
    if (threadIdx.x == 0) w[c] = (red[0] + red[1]) + (red[2] + red[3]);
}

// ---------------------------------------------------------------------------
// Kernel 3 (fused copy + u-partials): block = (j-tile of 256 cols, chunk of
// 32 row-pairs). Copies rows c and c+D to out while accumulating
//   upart[cy][j] = sum_{c in chunk} w[c] * (Z[c+D,j] - Z[c,j])
// Covers out rows 0..1023 entirely (all 8193 columns).
// ---------------------------------------------------------------------------
__global__ void k_u(const float* __restrict__ Z, const float* __restrict__ w,
                    float* __restrict__ upart, float* __restrict__ out) {
    int j = blockIdx.x * 256 + threadIdx.x;
    if (j >= NP1) return;
    int c0 = blockIdx.y * 32;
    float acc = 0.0f;
#pragma unroll 4
    for (int c = c0; c < c0 + 32; ++c) {
        size_t olo = (size_t)c * NP1 + j;
        size_t ohi = (size_t)(c + ND) * NP1 + j;
        float lo = Z[olo];
        float hi = Z[ohi];
        out[olo] = lo;
        out[ohi] = hi;
        acc = fmaf(w[c], hi - lo, acc);
    }
    upart[(size_t)blockIdx.y * NP1 + j] = acc;
}

// ---------------------------------------------------------------------------
// Kernel 4: last row: out[2D, j] = Z[2D, j] + (alpha/N) * sum_k upart[k][j]
// ---------------------------------------------------------------------------
__global__ void k_fin(const float* __restrict__ Z, const float* __restrict__ upart,
                      const float* __restrict__ alpha, float* __restrict__ out) {
    int j = blockIdx.x * 256 + threadIdx.x;
    if (j >= NP1) return;
    float u = 0.0f;
#pragma unroll
    for (int k = 0; k < NCHUNK; ++k) u += upart[(size_t)k * NP1 + j];
    float s = alpha[0] / (float)NN;
    const size_t off = (size_t)(2 * ND) * NP1 + j;
    out[off] = fmaf(s, u, Z[off]);
}

extern "C" void kernel_launch(void* const* d_in, const int* in_sizes, int n_in,
                              void* d_out, int out_size, void* d_ws, size_t ws_size,
                              hipStream_t stream) {
    const float* Z     = (const float*)d_in[0];
    const float* alpha = (const float*)d_in[1];
    // d_in[2..4] = P, M, Q: structure hardcoded (P one-hot at [-1,-1],
    // M = lmbd^(i-j) lower-tri with zero last row/col, Q = [[-I, I], [0, 0]]).
    float* out = (float*)d_out;

    // workspace layout (floats): v[NP1] | w[ND] | upart[NCHUNK*NP1]  (~560 KB)
    float* v     = (float*)d_ws;
    float* w     = v + NP1;
    float* upart = w + ND;

    // 1) decayed suffix scan of last row (4 lanes per column)
    k_v<<<(NP1 + 63) / 64, 256, 0, stream>>>(Z, v);
    // 2) w = Z[0:D,:] @ v
    k_w<<<ND, 1024, 0, stream>>>(Z, v, w);
    // 3) fused: out rows 0..1023 = Z rows 0..1023, plus u partials
    dim3 gu((NP1 + 255) / 256, NCHUNK);
    k_u<<<gu, 256, 0, stream>>>(Z, w, upart, out);
    // 4) last row update
    k_fin<<<(NP1 + 255) / 256, 256, 0, stream>>>(Z, upart, alpha, out);
}

// Round 3
// 29.864 us; speedup vs baseline: 2.1257x; 1.0710x over previous
//
#include <hip/hip_runtime.h>

// Problem constants (match reference file)
#define ND   512          // D
#define NN   8192         // N
#define NP1  8193         // N+1
#define NROWS 1025        // 2D+1
#define NCHUNK 32         // row-pair chunks for u partials (16 rows each)

// ---------------------------------------------------------------------------
// Kernel 1: v[j] = sum_{k>=0} z[j+k] * lmbd^k, z = last row of Z.
// Truncated at 192 terms (0.9^192/(1-0.9) ~ 1.6e-8, way below threshold).
// 4 lanes cooperate per column j (48 terms each), shfl_xor combine.
// ---------------------------------------------------------------------------
__global__ void k_v(const float* __restrict__ Z, float* __restrict__ v) {
    int tid = threadIdx.x;
    int jj = blockIdx.x * 64 + (tid >> 2);
    if (jj > NN) return;
    int p = tid & 3;
    if (jj == NN) { if (p == 0) v[jj] = 0.0f; return; }
    const float* z = Z + (size_t)(2 * ND) * NP1;
    const float l1 = 0.9f;
    const float l2 = l1 * l1, l4 = l2 * l2, l8 = l4 * l4;
    const float l16 = l8 * l8, l32 = l16 * l16, l48 = l32 * l16;
    float scale = (p == 0) ? 1.0f
                : (p == 1) ? l48
                : (p == 2) ? l48 * l48
                           : l48 * l48 * l48;
    int base = jj + 48 * p;
    float p0 = scale, p1 = scale * l1, p2 = scale * l2, p3 = scale * l2 * l1;
    float a0 = 0.f, a1 = 0.f, a2 = 0.f, a3 = 0.f;
#pragma unroll
    for (int m = 0; m < 48; m += 4) {
        int i = base + m;
        float z0 = (i     < NN) ? z[i]     : 0.0f;
        float z1 = (i + 1 < NN) ? z[i + 1] : 0.0f;
        float z2 = (i + 2 < NN) ? z[i + 2] : 0.0f;
        float z3 = (i + 3 < NN) ? z[i + 3] : 0.0f;
        a0 = fmaf(p0, z0, a0);
        a1 = fmaf(p1, z1, a1);
        a2 = fmaf(p2, z2, a2);
        a3 = fmaf(p3, z3, a3);
        p0 *= l4; p1 *= l4; p2 *= l4; p3 *= l4;
    }
    float a = (a0 + a2) + (a1 + a3);
    a += __shfl_xor(a, 1, 64);
    a += __shfl_xor(a, 2, 64);
    if (p == 0) v[jj] = a;
}

// ---------------------------------------------------------------------------
// Kernel 2: w[c] = sum_{j<N} Z[c,j] * v[j], one block (1024 thr) per row c < D.
// 8 independent accumulator chains -> 8 loads in flight per thread.
// ---------------------------------------------------------------------------
__global__ void k_w(const float* __restrict__ Z, const float* __restrict__ v,
                    float* __restrict__ w) {
    int c = blockIdx.x;
    const float* row = Z + (size_t)c * NP1;
    int t = threadIdx.x;
    float a0 = 0.f, a1 = 0.f, a2 = 0.f, a3 = 0.f;
    float a4 = 0.f, a5 = 0.f, a6 = 0.f, a7 = 0.f;
    // NN = 8192 = 8 * 1024 exactly: one pass, 8 chains
    {
        int j = t;
        a0 = fmaf(row[j        ], v[j        ], a0);
        a1 = fmaf(row[j + 1024 ], v[j + 1024 ], a1);
        a2 = fmaf(row[j + 2048 ], v[j + 2048 ], a2);
        a3 = fmaf(row[j + 3072 ], v[j + 3072 ], a3);
        a4 = fmaf(row[j + 4096 ], v[j + 4096 ], a4);
        a5 = fmaf(row[j + 5120 ], v[j + 5120 ], a5);
        a6 = fmaf(row[j + 6144 ], v[j + 6144 ], a6);
        a7 = fmaf(row[j + 7168 ], v[j + 7168 ], a7);
    }
    float acc = ((a0 + a1) + (a2 + a3)) + ((a4 + a5) + (a6 + a7));
    for (int off = 32; off > 0; off >>= 1)
        acc += __shfl_down(acc, off, 64);
    __shared__ float red[16];
    if ((t & 63) == 0) red[t >> 6] = acc;
    __syncthreads();
    if (t == 0) {
        float s = 0.f;
#pragma unroll
        for (int k = 0; k < 16; ++k) s += red[k];
        w[c] = s;
    }
}

// ---------------------------------------------------------------------------
// Kernel 3 (fused copy + u-partials): block = (j-tile of 256 cols, chunk of
// 16 row-pairs). Copies rows c and c+D to out (nontemporal) while accumulating
//   upart[cy][j] = sum_{c in chunk} w[c] * (Z[c+D,j] - Z[c,j])
// Batches 4 row-pairs: 8 loads in flight before stores/FMAs.
// ---------------------------------------------------------------------------
__global__ void k_u(const float* __restrict__ Z, const float* __restrict__ w,
                    float* __restrict__ upart, float* __restrict__ out) {
    int j = blockIdx.x * 256 + threadIdx.x;
    if (j >= NP1) return;
    int c0 = blockIdx.y * 16;
    const size_t DSTRIDE = (size_t)ND * NP1;
    float acc0 = 0.0f, acc1 = 0.0f;
#pragma unroll
    for (int cb = 0; cb < 16; cb += 4) {
        size_t b0 = (size_t)(c0 + cb) * NP1 + j;
        size_t b1 = b0 + NP1;
        size_t b2 = b1 + NP1;
        size_t b3 = b2 + NP1;
        float lo0 = Z[b0], lo1 = Z[b1], lo2 = Z[b2], lo3 = Z[b3];
        float hi0 = Z[b0 + DSTRIDE], hi1 = Z[b1 + DSTRIDE];
        float hi2 = Z[b2 + DSTRIDE], hi3 = Z[b3 + DSTRIDE];
        __builtin_nontemporal_store(lo0, &out[b0]);
        __builtin_nontemporal_store(lo1, &out[b1]);
        __builtin_nontemporal_store(lo2, &out[b2]);
        __builtin_nontemporal_store(lo3, &out[b3]);
        __builtin_nontemporal_store(hi0, &out[b0 + DSTRIDE]);
        __builtin_nontemporal_store(hi1, &out[b1 + DSTRIDE]);
        __builtin_nontemporal_store(hi2, &out[b2 + DSTRIDE]);
        __builtin_nontemporal_store(hi3, &out[b3 + DSTRIDE]);
        acc0 = fmaf(w[c0 + cb    ], hi0 - lo0, acc0);
        acc1 = fmaf(w[c0 + cb + 1], hi1 - lo1, acc1);
        acc0 = fmaf(w[c0 + cb + 2], hi2 - lo2, acc0);
        acc1 = fmaf(w[c0 + cb + 3], hi3 - lo3, acc1);
    }
    upart[(size_t)blockIdx.y * NP1 + j] = acc0 + acc1;
}

// ---------------------------------------------------------------------------
// Kernel 4: last row: out[2D, j] = Z[2D, j] + (alpha/N) * sum_k upart[k][j]
// ---------------------------------------------------------------------------
__global__ void k_fin(const float* __restrict__ Z, const float* __restrict__ upart,
                      const float* __restrict__ alpha, float* __restrict__ out) {
    int j = blockIdx.x * 256 + threadIdx.x;
    if (j >= NP1) return;
    float u0 = 0.0f, u1 = 0.0f;
#pragma unroll
    for (int k = 0; k < NCHUNK; k += 2) {
        u0 += upart[(size_t)k * NP1 + j];
        u1 += upart[(size_t)(k + 1) * NP1 + j];
    }
    float s = alpha[0] / (float)NN;
    const size_t off = (size_t)(2 * ND) * NP1 + j;
    out[off] = fmaf(s, u0 + u1, Z[off]);
}

extern "C" void kernel_launch(void* const* d_in, const int* in_sizes, int n_in,
                              void* d_out, int out_size, void* d_ws, size_t ws_size,
                              hipStream_t stream) {
    const float* Z     = (const float*)d_in[0];
    const float* alpha = (const float*)d_in[1];
    // d_in[2..4] = P, M, Q: structure hardcoded (P one-hot at [-1,-1],
    // M = lmbd^(i-j) lower-tri with zero last row/col, Q = [[-I, I], [0, 0]]).
    float* out = (float*)d_out;

    // workspace layout (floats): v[NP1] | w[ND] | upart[NCHUNK*NP1]  (~1.1 MB)
    float* v     = (float*)d_ws;
    float* w     = v + NP1;
    float* upart = w + ND;

    // 1) decayed suffix scan of last row (4 lanes per column)
    k_v<<<(NP1 + 63) / 64, 256, 0, stream>>>(Z, v);
    // 2) w = Z[0:D,:] @ v  (also warms rows 0..511 into L3 for k_u)
    k_w<<<ND, 1024, 0, stream>>>(Z, v, w);
    // 3) fused: out rows 0..1023 = Z rows 0..1023 (nontemporal), plus u partials
    dim3 gu((NP1 + 255) / 256, NCHUNK);
    k_u<<<gu, 256, 0, stream>>>(Z, w, upart, out);
    // 4) last row update
    k_fin<<<(NP1 + 255) / 256, 256, 0, stream>>>(Z, upart, alpha, out);
}

// Round 5
// 27.307 us; speedup vs baseline: 2.3248x; 1.0937x over previous
//
#include <hip/hip_runtime.h>

// Problem constants (match reference file)
#define ND   512          // D
#define NN   8192         // N
#define NP1  8193         // N+1
#define NCHUNK 32         // c-chunks for u partials (16 rows each)

typedef float f4 __attribute__((ext_vector_type(4)));

// ---------------------------------------------------------------------------
// K1: blocks 0..128 compute v[j] = sum_{k>=0} z[j+k]*0.9^k (trunc 192, 4
// lanes/column); blocks 129..1023 copy rows 512..1023 of Z to out (flat
// float4, nontemporal stores; plain loads so hi rows land in L3 for K3).
// ---------------------------------------------------------------------------
__global__ void k1_v_hicopy(const float* __restrict__ Z, float* __restrict__ v,
                            float* __restrict__ out) {
    int b = blockIdx.x;
    if (b < 129) {
        int tid = threadIdx.x;
        int jj = b * 64 + (tid >> 2);
        if (jj > NN) return;
        int p = tid & 3;
        if (jj == NN) { if (p == 0) v[jj] = 0.0f; return; }
        const float* z = Z + (size_t)(2 * ND) * NP1;
        const float l1 = 0.9f;
        const float l2 = l1 * l1, l4 = l2 * l2, l8 = l4 * l4;
        const float l16 = l8 * l8, l32 = l16 * l16, l48 = l32 * l16;
        float scale = (p == 0) ? 1.0f
                    : (p == 1) ? l48
                    : (p == 2) ? l48 * l48
                               : l48 * l48 * l48;
        int base = jj + 48 * p;
        float p0 = scale, p1 = scale * l1, p2 = scale * l2, p3 = scale * l2 * l1;
        float a0 = 0.f, a1 = 0.f, a2 = 0.f, a3 = 0.f;
#pragma unroll
        for (int m = 0; m < 48; m += 4) {
            int i = base + m;
            float z0 = (i     < NN) ? z[i]     : 0.0f;
            float z1 = (i + 1 < NN) ? z[i + 1] : 0.0f;
            float z2 = (i + 2 < NN) ? z[i + 2] : 0.0f;
            float z3 = (i + 3 < NN) ? z[i + 3] : 0.0f;
            a0 = fmaf(p0, z0, a0);
            a1 = fmaf(p1, z1, a1);
            a2 = fmaf(p2, z2, a2);
            a3 = fmaf(p3, z3, a3);
            p0 *= l4; p1 *= l4; p2 *= l4; p3 *= l4;
        }
        float a = (a0 + a2) + (a1 + a3);
        a += __shfl_xor(a, 1, 64);
        a += __shfl_xor(a, 2, 64);
        if (p == 0) v[jj] = a;
    } else {
        // rows 512..1023: floats [512*8193, 1024*8193) = 4,194,816 floats,
        // exactly 1,048,704 float4s starting at float4-index 1,048,704.
        const f4* src = (const f4*)Z + 1048704u;
        f4*       dst = (f4*)out     + 1048704u;
        const unsigned STR = 895u * 256u;
        unsigned i = (unsigned)(b - 129) * 256u + threadIdx.x;
        while (i + STR < 1048704u) {
            f4 x0 = src[i];
            f4 x1 = src[i + STR];
            __builtin_nontemporal_store(x0, &dst[i]);
            __builtin_nontemporal_store(x1, &dst[i + STR]);
            i += 2u * STR;
        }
        if (i < 1048704u) {
            f4 x0 = src[i];
            __builtin_nontemporal_store(x0, &dst[i]);
        }
    }
}

// ---------------------------------------------------------------------------
// K2 (fused w + lo-copy): one block (1024 thr) per row c < 512.
// w[c] = sum_{j<N} Z[c,j]*v[j]; row is also stored to out.
// ---------------------------------------------------------------------------
__global__ __launch_bounds__(1024) void k2_wcopy(const float* __restrict__ Z,
                                                 const float* __restrict__ v,
                                                 float* __restrict__ w,
                                                 float* __restrict__ out) {
    int c = blockIdx.x;
    const float* row = Z + (size_t)c * NP1;
    float* orow = out + (size_t)c * NP1;
    int t = threadIdx.x;
    float r0 = row[t        ], r1 = row[t + 1024 ], r2 = row[t + 2048 ], r3 = row[t + 3072 ];
    float r4 = row[t + 4096 ], r5 = row[t + 5120 ], r6 = row[t + 6144 ], r7 = row[t + 7168 ];
    __builtin_nontemporal_store(r0, &orow[t        ]);
    __builtin_nontemporal_store(r1, &orow[t + 1024 ]);
    __builtin_nontemporal_store(r2, &orow[t + 2048 ]);
    __builtin_nontemporal_store(r3, &orow[t + 3072 ]);
    __builtin_nontemporal_store(r4, &orow[t + 4096 ]);
    __builtin_nontemporal_store(r5, &orow[t + 5120 ]);
    __builtin_nontemporal_store(r6, &orow[t + 6144 ]);
    __builtin_nontemporal_store(r7, &orow[t + 7168 ]);
    if (t == 0) orow[NN] = row[NN];   // column 8192 (v[NN]=0, copy only)
    float acc = 0.f;
    acc = fmaf(r0, v[t        ], acc);
    acc = fmaf(r1, v[t + 1024 ], acc);
    acc = fmaf(r2, v[t + 2048 ], acc);
    acc = fmaf(r3, v[t + 3072 ], acc);
    acc = fmaf(r4, v[t + 4096 ], acc);
    acc = fmaf(r5, v[t + 5120 ], acc);
    acc = fmaf(r6, v[t + 6144 ], acc);
    acc = fmaf(r7, v[t + 7168 ], acc);
    for (int off = 32; off > 0; off >>= 1)
        acc += __shfl_down(acc, off, 64);
    __shared__ float red[16];
    if ((t & 63) == 0) red[t >> 6] = acc;
    __syncthreads();
    if (t == 0) {
        float s = 0.f;
#pragma unroll
        for (int k = 0; k < 16; ++k) s += red[k];
        w[c] = s;
    }
}

// ---------------------------------------------------------------------------
// K3 (compute-only u partials): Z fully L3-resident now.
//   upart[cy][j] = sum_{c in 16-chunk} w[c] * (Z[c+D,j] - Z[c,j])
// ---------------------------------------------------------------------------
__global__ void k3_u(const float* __restrict__ Z, const float* __restrict__ w,
                     float* __restrict__ upart) {
    int j = blockIdx.x * 256 + threadIdx.x;
    if (j >= NP1) return;
    int c0 = blockIdx.y * 16;
    const size_t DS = (size_t)ND * NP1;
    float acc0 = 0.f, acc1 = 0.f;
#pragma unroll
    for (int cb = 0; cb < 16; cb += 4) {
        size_t b0 = (size_t)(c0 + cb) * NP1 + j;
        size_t b1 = b0 + NP1;
        size_t b2 = b1 + NP1;
        size_t b3 = b2 + NP1;
        float lo0 = Z[b0], lo1 = Z[b1], lo2 = Z[b2], lo3 = Z[b3];
        float hi0 = Z[b0 + DS], hi1 = Z[b1 + DS], hi2 = Z[b2 + DS], hi3 = Z[b3 + DS];
        acc0 = fmaf(w[c0 + cb    ], hi0 - lo0, acc0);
        acc1 = fmaf(w[c0 + cb + 1], hi1 - lo1, acc1);
        acc0 = fmaf(w[c0 + cb + 2], hi2 - lo2, acc0);
        acc1 = fmaf(w[c0 + cb + 3], hi3 - lo3, acc1);
    }
    upart[(size_t)blockIdx.y * NP1 + j] = acc0 + acc1;
}

// ---------------------------------------------------------------------------
// K4: last row: out[2D, j] = Z[2D, j] + (alpha/N) * sum_k upart[k][j]
// 4 lanes per column, 8 chunks each, quad shfl combine.
// ---------------------------------------------------------------------------
__global__ void k4_fin(const float* __restrict__ Z, const float* __restrict__ upart,
                       const float* __restrict__ alpha, float* __restrict__ out) {
    int gid = blockIdx.x * 256 + threadIdx.x;
    int j = gid >> 2;
    if (j >= NP1) return;
    int p = gid & 3;
    float u = 0.f;
#pragma unroll
    for (int k = p * 8; k < p * 8 + 8; ++k)
        u += upart[(size_t)k * NP1 + j];
    u += __shfl_xor(u, 1, 64);
    u += __shfl_xor(u, 2, 64);
    if (p == 0) {
        float s = alpha[0] / (float)NN;
        const size_t off = (size_t)(2 * ND) * NP1 + j;
        out[off] = fmaf(s, u, Z[off]);
    }
}

extern "C" void kernel_launch(void* const* d_in, const int* in_sizes, int n_in,
                              void* d_out, int out_size, void* d_ws, size_t ws_size,
                              hipStream_t stream) {
    const float* Z     = (const float*)d_in[0];
    const float* alpha = (const float*)d_in[1];
    // d_in[2..4] = P, M, Q: structure hardcoded (P one-hot at [-1,-1],
    // M = lmbd^(i-j) lower-tri with zero last row/col, Q = [[-I, I], [0, 0]]).
    float* out = (float*)d_out;

    // workspace layout (floats): v[NP1] | w[ND] | upart[NCHUNK*NP1]  (~1.1 MB)
    float* v     = (float*)d_ws;
    float* w     = v + NP1;
    float* upart = w + ND;

    // 1) v (129 blocks) + hi-row copy (895 blocks) fused
    k1_v_hicopy<<<1024, 256, 0, stream>>>(Z, v, out);
    // 2) w = Z[0:D,:] @ v, fused with lo-row copy to out
    k2_wcopy<<<ND, 1024, 0, stream>>>(Z, v, w, out);
    // 3) u partials, Z read from L3 (no HBM fetch expected)
    dim3 gu((NP1 + 255) / 256, NCHUNK);
    k3_u<<<gu, 256, 0, stream>>>(Z, w, upart);
    // 4) last row update
    k4_fin<<<(4 * NP1 + 255) / 256, 256, 0, stream>>>(Z, upart, alpha, out);
}